// Round 1
// baseline (678.831 us; speedup 1.0000x reference)
//
#include <hip/hip_runtime.h>

// ChebyshevKAN on MI355X (gfx950).
// Reformulation: einsum(bid,oid->bo) + x@base_w.T  ==  Xaug @ W^T with
//   Xaug[b, i*6+d] = T_{d+1}(tanh(x_i))  (d=0..4),  Xaug[b, i*6+5] = x_i
//   W[o,    i*6+d] = coeff[o,i,d+1]      (d=0..4),  W[o,    i*6+5] = base_w[o,i]
// T0==1 slice folds into bias:  bias'[o] = bias[o] + sum_i coeff[o,i,0].
//
// R6: replace the m97-style 128x128 single-buffer GEMM (measured ~800 TF,
// MfmaUtil 34%) with the 256-wide 8-phase schedule (T2+T3+T4+T5):
//  - 512 threads (8 waves, 2Mx4N), BM=256, BK=64, double-buffered LDS
//    (128 KiB for BN=256), 1 block/CU, grid = (rows/256)*4 = 256 blocks.
//  - per phase: {ds_read frag subtile || issue global_load_lds prefetch}
//    -> s_barrier -> lgkmcnt(0) -> setprio(1) MFMA quad setprio(0) -> s_barrier.
//  - counted vmcnt: vmcnt(8) (BN=256) / vmcnt(6) (BN=128) at phases 4 and 8
//    only; never 0 in the main loop. Ledger: at ph4's vmcnt(8) the newest 8
//    loads are ph3(B,4)+ph4(A,4) of the NEXT even tile, so the odd tile
//    (staged prev iter ph7/8) is guaranteed landed before ph5 reads it.
//    WAR: buf0.B last read ph2 (staged ph3), buf0.A last read ph3 (staged
//    ph4), buf1.B last read ph6 (staged ph7), buf1.A last read ph7 (staged
//    ph8) -- each stage site is exactly one full barrier after the last read.
//  - chunk-XOR LDS swizzle + width-16 global_load_lds carried over unchanged
//    from the verified R5 kernel (SQ_LDS_BANK_CONFLICT == 0).
// GEMM2 uses BN=128 so N=512 still gives 256 blocks (full machine).

typedef __bf16 bf16x8 __attribute__((ext_vector_type(8)));
typedef float f32x4 __attribute__((ext_vector_type(4)));
typedef unsigned short u16x8 __attribute__((ext_vector_type(8)));

__device__ __forceinline__ unsigned short f2bf(float f) {
    unsigned int u = __float_as_uint(f);
    unsigned int r = (u + 0x7FFFu + ((u >> 16) & 1u)) >> 16;
    return (unsigned short)r;
}
__device__ __forceinline__ float bf2f(unsigned short b) {
    return __uint_as_float(((unsigned int)b) << 16);
}

// tanh via hardware exp/rcp: err ~1e-6, way below bf16 quantization.
__device__ __forceinline__ float fast_tanh(float x) {
    float a = fminf(fmaxf(x, -15.f), 15.f);
    float e = __expf(2.f * a);
    return 1.f - 2.f * __builtin_amdgcn_rcpf(e + 1.f);
}
__device__ __forceinline__ float fast_silu(float y) {
    float a = fminf(fmaxf(y, -30.f), 30.f);
    return y * __builtin_amdgcn_rcpf(1.f + __expf(-a));
}

__device__ __forceinline__ void cheb_pack(float s, unsigned short* o6) {
    float u  = fast_tanh(s);
    float T1 = u;
    float T2 = 2.f * u * u - 1.f;
    float T3 = 2.f * u * T2 - T1;
    float T4 = 2.f * u * T3 - T2;
    float T5 = 2.f * u * T4 - T3;
    o6[0] = f2bf(T1); o6[1] = f2bf(T2); o6[2] = f2bf(T3);
    o6[3] = f2bf(T4); o6[4] = f2bf(T5); o6[5] = f2bf(s);
}

__device__ __forceinline__ void load_lds16(const void* g, void* l) {
    __builtin_amdgcn_global_load_lds(
        (const __attribute__((address_space(1))) void*)g,
        (__attribute__((address_space(3))) void*)l, 16, 0, 0);
}

// ---------------- prep: weights [O,I,6]+[O,I] -> W[N=O, K=I*6] bf16 ----------
__global__ __launch_bounds__(256) void prep_w_kernel(
    const float* __restrict__ coeff, const float* __restrict__ base_w,
    unsigned short* __restrict__ W, int OI)
{
    int idx = blockIdx.x * 256 + threadIdx.x;
    if (idx >= OI) return;
    const float* c = coeff + (size_t)idx * 6;
    unsigned short w0 = f2bf(c[1]), w1 = f2bf(c[2]), w2 = f2bf(c[3]),
                   w3 = f2bf(c[4]), w4 = f2bf(c[5]), w5 = f2bf(base_w[idx]);
    unsigned int* d = (unsigned int*)(W + (size_t)idx * 6);
    d[0] = w0 | ((unsigned int)w1 << 16);
    d[1] = w2 | ((unsigned int)w3 << 16);
    d[2] = w4 | ((unsigned int)w5 << 16);
}

// bias'[o] = bias[o] + sum_i coeff[o,i,0]   (fp32, block per o)
__global__ __launch_bounds__(256) void prep_bias_kernel(
    const float* __restrict__ coeff, const float* __restrict__ bias,
    float* __restrict__ bp, int I)
{
    int o = blockIdx.x, tid = threadIdx.x;
    float s = 0.f;
    for (int i = tid; i < I; i += 256) s += coeff[((size_t)o * I + i) * 6];
    #pragma unroll
    for (int off = 32; off > 0; off >>= 1) s += __shfl_down(s, off);
    __shared__ float red[4];
    int lane = tid & 63, wv = tid >> 6;
    if (lane == 0) red[wv] = s;
    __syncthreads();
    if (tid == 0) bp[o] = bias[o] + red[0] + red[1] + red[2] + red[3];
}

// ---------------- expand1: x[b,1024] -> Xaug[b,6144] bf16  (block per row) ---
__global__ __launch_bounds__(256) void expand1_kernel(
    const float* __restrict__ x, unsigned short* __restrict__ Xa)
{
    int b = blockIdx.x, tid = threadIdx.x;
    f32x4 xv = *(const f32x4*)(x + (size_t)b * 1024 + tid * 4);
    alignas(16) unsigned short ov[24];
    #pragma unroll
    for (int e = 0; e < 4; e++) cheb_pack(fast_tanh(xv[e]), ov + e * 6);
    u16x8* dst = (u16x8*)(Xa + (size_t)b * 6144 + tid * 24);
    const u16x8* src = (const u16x8*)ov;
    dst[0] = src[0]; dst[1] = src[1]; dst[2] = src[2];
}

// ------------- LN + SiLU + expand2 fused (block per row of 1024, h in bf16) --
__global__ __launch_bounds__(256) void ln_silu_expand_kernel(
    const unsigned short* __restrict__ H, const float* __restrict__ gamma,
    const float* __restrict__ beta, unsigned short* __restrict__ Xa)
{
    int b = blockIdx.x, tid = threadIdx.x;
    ushort4 hb = *(const ushort4*)(H + (size_t)b * 1024 + tid * 4);
    float hv[4] = { bf2f(hb.x), bf2f(hb.y), bf2f(hb.z), bf2f(hb.w) };
    float s1 = hv[0] + hv[1] + hv[2] + hv[3];
    float s2 = hv[0]*hv[0] + hv[1]*hv[1] + hv[2]*hv[2] + hv[3]*hv[3];
    #pragma unroll
    for (int off = 32; off > 0; off >>= 1) {
        s1 += __shfl_down(s1, off);
        s2 += __shfl_down(s2, off);
    }
    __shared__ float red[8];
    __shared__ float stats[2];
    int lane = tid & 63, wv = tid >> 6;
    if (lane == 0) { red[wv] = s1; red[4 + wv] = s2; }
    __syncthreads();
    if (tid == 0) {
        float t1 = red[0] + red[1] + red[2] + red[3];
        float t2 = red[4] + red[5] + red[6] + red[7];
        float mu = t1 * (1.f / 1024.f);
        float var = t2 * (1.f / 1024.f) - mu * mu;
        stats[0] = mu;
        stats[1] = rsqrtf(var + 1e-5f);
    }
    __syncthreads();
    float mu = stats[0], rs = stats[1];
    f32x4 g  = *(const f32x4*)(gamma + tid * 4);
    f32x4 bt = *(const f32x4*)(beta  + tid * 4);
    alignas(16) unsigned short ov[24];
    #pragma unroll
    for (int e = 0; e < 4; e++) {
        float y = (hv[e] - mu) * rs * g[e] + bt[e];
        cheb_pack(fast_silu(y), ov + e * 6);
    }
    u16x8* dst = (u16x8*)(Xa + (size_t)b * 6144 + tid * 24);
    const u16x8* src = (const u16x8*)ov;
    dst[0] = src[0]; dst[1] = src[1]; dst[2] = src[2];
}

// ---------------- 8-phase bf16 GEMM: C[M,N] = A[M,K] * W[N,K]^T + bias ------
#define FENCE() asm volatile("" ::: "memory")

#define PH_MID() do { \
    FENCE(); __builtin_amdgcn_s_barrier(); \
    asm volatile("s_waitcnt lgkmcnt(0)" ::: "memory"); \
    __builtin_amdgcn_sched_barrier(0); \
    __builtin_amdgcn_s_setprio(1); } while (0)

#define PH_END() do { \
    __builtin_amdgcn_s_setprio(0); \
    FENCE(); __builtin_amdgcn_s_barrier(); FENCE(); } while (0)

#define VM_STEADY() do { \
    if constexpr (BN == 256) asm volatile("s_waitcnt vmcnt(8)" ::: "memory"); \
    else                     asm volatile("s_waitcnt vmcnt(6)" ::: "memory"); } while (0)
#define VM_DRAIN() asm volatile("s_waitcnt vmcnt(0)" ::: "memory")

// read 4 A-frags (both k-halves) for quadrant MH of the wave's 128 rows
#define RD_A(DST0, DST1, BASE, MH) do { \
    _Pragma("unroll") \
    for (int mf = 0; mf < 4; ++mf) { \
        const unsigned short* p_ = (BASE) + ((MH) * 64 + mf * 16) * 64; \
        DST0[mf] = *(const bf16x8*)(p_ + c0); \
        DST1[mf] = *(const bf16x8*)(p_ + c1); \
    } } while (0)

// read FN B-frags at one k-half
#define RD_B(DST, BASE, CSEL) do { \
    _Pragma("unroll") \
    for (int nf = 0; nf < FN; ++nf) \
        DST[nf] = *(const bf16x8*)((BASE) + (nf * 16) * 64 + (CSEL)); \
    } while (0)

#define QUAD(MH, AV, BV) do { \
    _Pragma("unroll") \
    for (int mf = 0; mf < 4; ++mf) \
        _Pragma("unroll") \
        for (int nf = 0; nf < FN; ++nf) \
            acc[MH][mf][nf] = __builtin_amdgcn_mfma_f32_16x16x32_bf16( \
                AV[mf], BV[nf], acc[MH][mf][nf], 0, 0, 0); \
    } while (0)

template<int BN, bool OUT_BF16>
__global__ __launch_bounds__(512, 2) void gemm8_kernel(
    const unsigned short* __restrict__ A,   // [M,K] bf16 bits
    const unsigned short* __restrict__ Wt,  // [N,K] bf16 bits
    const float* __restrict__ bias,         // [N]
    void* __restrict__ Cout,                // [M,N] f32 or bf16
    int N, int K, int NMT)
{
    constexpr int FN   = BN / 64;   // n-frags per wave (4 or 2)
    constexpr int BUPW = BN / 64;   // B stage-units per wave (4 or 2)

    __shared__ __align__(16) unsigned short As[2 * 256 * 64];
    __shared__ __align__(16) unsigned short Bs[2 * BN * 64];

    const int tid  = threadIdx.x;
    const int lane = tid & 63;
    const int wave = tid >> 6;
    const int wm   = wave >> 2;     // 0..1
    const int wn   = wave & 3;      // 0..3

    // XCD-affinity swizzle (bijective when nwg%8==0; else identity)
    int wg = blockIdx.x;
    {
        const int nwg = gridDim.x;
        if ((nwg & 7) == 0) {
            const int cpx = nwg >> 3;
            wg = (wg & 7) * cpx + (wg >> 3);
        }
    }
    const int mt = wg % NMT;
    const int nt = wg / NMT;
    const size_t m0 = (size_t)mt * 256;
    const size_t n0 = (size_t)nt * BN;

    // staging lane offsets (chunk-XOR pre-swizzled global source, linear LDS)
    const int srow   = lane >> 3;
    const int schunk = (lane & 7) ^ (srow & 7);
    const unsigned short* Ag = A  + (m0 + srow) * (size_t)K + schunk * 8;
    const unsigned short* Bg = Wt + (n0 + srow) * (size_t)K + schunk * 8;

    // frag-read lane offsets (XOR de-swizzle on read)
    const int fr  = lane & 15;
    const int cg  = lane >> 4;
    const int fr7 = fr & 7;
    const int c0  = ((cg    ) ^ fr7) << 3;
    const int c1  = ((cg + 4) ^ fr7) << 3;

    const int NT = K >> 6;          // number of 64-wide K-tiles (even, >=2)

    // wave's frag base pointers per LDS buffer
    const unsigned short* A0f = As + fr * 64 + (wm * 128) * 64;      // buf0
    const unsigned short* A1f = A0f + 256 * 64;                      // buf1
    const unsigned short* B0f = Bs + fr * 64 + (wn * (BN / 4)) * 64; // buf0
    const unsigned short* B1f = B0f + BN * 64;                       // buf1

    auto stageA = [&](int kt, int bsel) {
        const unsigned short* g = Ag + kt * 64;
        unsigned short* l = As + bsel * (256 * 64);
        #pragma unroll
        for (int j = 0; j < 4; ++j) {
            const int u = wave * 4 + j;
            load_lds16(g + (size_t)(u * 8) * K, l + u * 512);
        }
    };
    auto stageB = [&](int kt, int bsel) {
        const unsigned short* g = Bg + kt * 64;
        unsigned short* l = Bs + bsel * (BN * 64);
        #pragma unroll
        for (int j = 0; j < BUPW; ++j) {
            const int u = wave * BUPW + j;
            load_lds16(g + (size_t)(u * 8) * K, l + u * 512);
        }
    };

    f32x4 acc[2][4][FN];
    #pragma unroll
    for (int mh = 0; mh < 2; ++mh)
        #pragma unroll
        for (int mf = 0; mf < 4; ++mf)
            #pragma unroll
            for (int nf = 0; nf < FN; ++nf)
                acc[mh][mf][nf] = f32x4{0.f, 0.f, 0.f, 0.f};

    // prologue: K0 -> buf0 (oldest 8/6 loads), K1 -> buf1; counted wait leaves
    // K1 in flight (gated by iter-0 ph4's steady vmcnt).
    stageB(0, 0); stageA(0, 0);
    stageB(1, 1); stageA(1, 1);
    VM_STEADY();
    FENCE(); __builtin_amdgcn_s_barrier(); FENCE();

    for (int kt = 0; kt < NT; kt += 2) {
        const bool st = (kt + 4) <= NT;   // stage tiles kt+2/kt+3 exist
        bf16x8 a0[4], a1[4], b0[FN], b1[FN];

        // phase 1: read A[mh0] (both kk) + B[kk0] of buf0; C(mh0,kk0)
        RD_A(a0, a1, A0f, 0);
        RD_B(b0, B0f, c0);
        PH_MID(); QUAD(0, a0, b0); PH_END();

        // phase 2: read B[kk1]; C(mh0,kk1)
        RD_B(b1, B0f, c1);
        PH_MID(); QUAD(0, a1, b1); PH_END();

        // phase 3: read A[mh1]; stage next-even B (buf0.B free since ph2)
        RD_A(a0, a1, A0f, 1);
        if (st) stageB(kt + 2, 0);
        PH_MID(); QUAD(1, a0, b0); PH_END();

        // phase 4: stage next-even A (buf0.A free since ph3); counted vmcnt
        //          guarantees buf1 (tile kt+1, staged last iter ph7/8) landed
        if (st) { stageA(kt + 2, 0); VM_STEADY(); }
        else    { VM_DRAIN(); }
        PH_MID(); QUAD(1, a1, b1); PH_END();

        // phase 5: buf1 reads begin
        RD_A(a0, a1, A1f, 0);
        RD_B(b0, B1f, c0);
        PH_MID(); QUAD(0, a0, b0); PH_END();

        // phase 6
        RD_B(b1, B1f, c1);
        PH_MID(); QUAD(0, a1, b1); PH_END();

        // phase 7: stage next-odd B (buf1.B free since ph6)
        RD_A(a0, a1, A1f, 1);
        if (st) stageB(kt + 3, 1);
        PH_MID(); QUAD(1, a0, b0); PH_END();

        // phase 8: stage next-odd A (buf1.A free since ph7); counted vmcnt
        //          guarantees buf0 (tile kt+2, staged ph3/4) landed for next iter
        if (st) { stageA(kt + 3, 1); VM_STEADY(); }
        else    { VM_DRAIN(); }
        PH_MID(); QUAD(1, a1, b1); PH_END();
    }

    // C/D layout (verified): col = lane&15, row = (lane>>4)*4 + reg
    const size_t rbase0 = m0 + wm * 128 + ((lane >> 4) << 2);
    const int cb = lane & 15;
    int colg[FN]; float bv[FN];
    #pragma unroll
    for (int nf = 0; nf < FN; ++nf) {
        colg[nf] = (int)n0 + wn * (BN / 4) + nf * 16 + cb;
        bv[nf] = bias[colg[nf]];
    }
    #pragma unroll
    for (int mh = 0; mh < 2; ++mh)
        #pragma unroll
        for (int mf = 0; mf < 4; ++mf) {
            const size_t rg0 = rbase0 + mh * 64 + mf * 16;
            #pragma unroll
            for (int r = 0; r < 4; ++r) {
                const size_t rowoff = (rg0 + r) * (size_t)N;
                #pragma unroll
                for (int nf = 0; nf < FN; ++nf) {
                    const float v = acc[mh][mf][nf][r] + bv[nf];
                    if constexpr (OUT_BF16)
                        ((unsigned short*)Cout)[rowoff + colg[nf]] = f2bf(v);
                    else
                        ((float*)Cout)[rowoff + colg[nf]] = v;
                }
            }
        }
}

extern "C" void kernel_launch(void* const* d_in, const int* in_sizes, int n_in,
                              void* d_out, int out_size, void* d_ws, size_t ws_size,
                              hipStream_t stream)
{
    const float* x       = (const float*)d_in[0];
    const float* coeff1  = (const float*)d_in[1];
    const float* base_w1 = (const float*)d_in[2];
    const float* bias1   = (const float*)d_in[3];
    const float* gamma   = (const float*)d_in[4];
    const float* beta    = (const float*)d_in[5];
    const float* coeff2  = (const float*)d_in[6];
    const float* base_w2 = (const float*)d_in[7];
    const float* bias2   = (const float*)d_in[8];
    float* out = (float*)d_out;

    const int B = 16384, D0 = 1024, D1 = 1024, D2 = 512;
    const int K1 = D0 * 6, K2 = D1 * 6;   // 6144 each

    // workspace layout
    char* base = (char*)d_ws;
    size_t off = 0;
    unsigned short* W1 = (unsigned short*)(base + off); off += (size_t)D1 * K1 * 2;
    unsigned short* W2 = (unsigned short*)(base + off); off += (size_t)D2 * K2 * 2;
    float* b1p = (float*)(base + off); off += (size_t)D1 * 4;
    float* b2p = (float*)(base + off); off += (size_t)D2 * 4;
    off = (off + 255) & ~(size_t)255;

    // chunk rows: Xaug (K1 bf16) + h (D1 bf16) per row; keep %256 (BM=256)
    size_t per_row = (size_t)K1 * 2 + (size_t)D1 * 2;   // 14336 B
    long long avail = (long long)ws_size - (long long)off;
    long long mcl = avail > 0 ? avail / (long long)per_row : 0;
    int Mc = (int)((mcl / 256) * 256);
    if (Mc < 256) Mc = 256;
    if (Mc > B) Mc = B;

    unsigned short* Xa = (unsigned short*)(base + off);
    unsigned short* h = (unsigned short*)(base + off + (size_t)Mc * K1 * 2);

    prep_w_kernel<<<(D1 * D0 + 255) / 256, 256, 0, stream>>>(coeff1, base_w1, W1, D1 * D0);
    prep_w_kernel<<<(D2 * D1 + 255) / 256, 256, 0, stream>>>(coeff2, base_w2, W2, D2 * D1);
    prep_bias_kernel<<<D1, 256, 0, stream>>>(coeff1, bias1, b1p, D0);
    prep_bias_kernel<<<D2, 256, 0, stream>>>(coeff2, bias2, b2p, D1);

    for (int m0 = 0; m0 < B; m0 += Mc) {
        int rows = (B - m0 < Mc) ? (B - m0) : Mc;
        int nmt = rows / 256;
        expand1_kernel<<<rows, 256, 0, stream>>>(x + (size_t)m0 * D0, Xa);
        gemm8_kernel<256, true><<<nmt * (D1 / 256), 512, 0, stream>>>(
            Xa, W1, b1p, h, D1, K1, nmt);
        ln_silu_expand_kernel<<<rows, 256, 0, stream>>>(h, gamma, beta, Xa);
        gemm8_kernel<128, false><<<nmt * (D2 / 128), 512, 0, stream>>>(
            Xa, W2, b2p, out + (size_t)m0 * D2, D2, K2, nmt);
    }
}